// Round 2
// baseline (1791.233 us; speedup 1.0000x reference)
//
#include <hip/hip_runtime.h>

// Problem constants
#define B_ 128
#define T_ 256
#define F_ 1024
#define C_ 512

// GEMM tiling: 128x128 block tile, BK=32, 256 threads, 8x8 per thread
#define BM 128
#define BN 128
#define BK 32
#define LDA_ (BM + 4)
#define LDB_ (BN + 4)

// ---------------------------------------------------------------------------
// GEMM: I[m, n] = sum_k X[row(m), k] * W[k, n]
//   m = chunk-local row = b*CT + tt ; global X row = b*T_ + t0 + tt
// Thread (ty,tx) computes rows {ty*4+i, 64+ty*4+i} x cols {tx*4+j, 64+tx*4+j}
// -> all LDS fragment reads are at 16B lane stride = conflict-free.
// ---------------------------------------------------------------------------
__global__ __launch_bounds__(256, 4) void snn_gemm_kernel(
    const float* __restrict__ X, const float* __restrict__ Wm,
    float* __restrict__ I, int t0, int CT, int lct) {
  __shared__ float As[BK][LDA_];  // transposed: As[k][m]
  __shared__ float Bs[BK][LDB_];

  const int tid = threadIdx.x;
  const int m0 = blockIdx.x * BM;
  const int n0 = blockIdx.y * BN;
  const int ctm1 = CT - 1;

  // Staging: A tile 128x32 = 1024 float4, B tile 32x128 = 1024 float4;
  // each thread owns 4 of each.
  const float* pA[4];
  const float* pB[4];
  int rowA[4], c4A[4], krB[4], cB[4];
#pragma unroll
  for (int j = 0; j < 4; ++j) {
    const int ia = tid + 256 * j;
    rowA[j] = ia >> 3;  // 0..127
    c4A[j] = ia & 7;    // k-group of 4 within BK=32
    const int mg = m0 + rowA[j];
    pA[j] = X + (size_t)((mg >> lct) * T_ + t0 + (mg & ctm1)) * F_ + c4A[j] * 4;
    krB[j] = ia >> 5;      // 0..31
    cB[j] = (ia & 31) * 4; // 0..124
    pB[j] = Wm + (size_t)krB[j] * C_ + n0 + cB[j];
  }

  const int ty = tid >> 4;  // 0..15
  const int tx = tid & 15;  // 0..15

  float4 ra[4], rb[4];
#pragma unroll
  for (int j = 0; j < 4; ++j) {
    ra[j] = *(const float4*)pA[j];
    rb[j] = *(const float4*)pB[j];
  }

  float acc[8][8] = {};

  for (int kt = 0; kt < F_ / BK; ++kt) {
    __syncthreads();
#pragma unroll
    for (int j = 0; j < 4; ++j) {
      As[c4A[j] * 4 + 0][rowA[j]] = ra[j].x;
      As[c4A[j] * 4 + 1][rowA[j]] = ra[j].y;
      As[c4A[j] * 4 + 2][rowA[j]] = ra[j].z;
      As[c4A[j] * 4 + 3][rowA[j]] = ra[j].w;
      *(float4*)&Bs[krB[j]][cB[j]] = rb[j];
    }
    __syncthreads();
    if (kt + 1 < F_ / BK) {
      const int k1 = (kt + 1) * BK;
#pragma unroll
      for (int j = 0; j < 4; ++j) {
        ra[j] = *(const float4*)(pA[j] + k1);
        rb[j] = *(const float4*)(pB[j] + (size_t)k1 * C_);
      }
    }
#pragma unroll
    for (int k = 0; k < BK; ++k) {
      const float4 a0 = *(const float4*)&As[k][ty * 4];
      const float4 a1 = *(const float4*)&As[k][64 + ty * 4];
      const float4 b0 = *(const float4*)&Bs[k][tx * 4];
      const float4 b1 = *(const float4*)&Bs[k][64 + tx * 4];
      const float av[8] = {a0.x, a0.y, a0.z, a0.w, a1.x, a1.y, a1.z, a1.w};
      const float bv[8] = {b0.x, b0.y, b0.z, b0.w, b1.x, b1.y, b1.z, b1.w};
#pragma unroll
      for (int i = 0; i < 8; ++i)
#pragma unroll
        for (int j = 0; j < 8; ++j) acc[i][j] += av[i] * bv[j];
    }
  }

  // epilogue
#pragma unroll
  for (int i = 0; i < 8; ++i) {
    const int m = m0 + ((i < 4) ? (ty * 4 + i) : (64 + ty * 4 + (i - 4)));
    float* op = I + (size_t)m * C_ + n0;
    *(float4*)(op + tx * 4) =
        make_float4(acc[i][0], acc[i][1], acc[i][2], acc[i][3]);
    *(float4*)(op + 64 + tx * 4) =
        make_float4(acc[i][4], acc[i][5], acc[i][6], acc[i][7]);
  }
}

// ---------------------------------------------------------------------------
// Scan: one thread per neuron (b,c). Branchless step (exact fp32 op order of
// the reference) + 16-deep double-buffered register prefetch of I.
// ---------------------------------------------------------------------------
#define GRP 16

#define STEP(Iv)                                                           \
  {                                                                        \
    const bool is0 = (mode == 0), is1 = (mode == 1), is2 = (mode == 2);    \
    V = is0 ? ((V + (Iv)) - 0.01f) : (is2 ? (V + 0.01f) : V);              \
    V = fmaxf(V, 0.0f);                                                    \
    const bool fired = is0 && ((V - 0.4f) > 0.0f);                         \
    sc += fired ? 1.0f : 0.0f;                                             \
    refr = fired ? 2.0f : (is1 ? fmaxf(refr - 1.0f, 0.0f) : refr);         \
    const bool done = is1 && (refr <= 0.0f);                               \
    const bool back = is2 && (V > 0.0f);                                   \
    V = fired ? 0.0f : V;                                                  \
    mode = fired ? 1 : (done ? 2 : (back ? 0 : mode));                     \
  }

__global__ __launch_bounds__(256) void snn_scan_kernel(
    const float* __restrict__ I, float* __restrict__ Vst,
    float* __restrict__ Rst, int* __restrict__ Mst, float* __restrict__ SCst,
    float* __restrict__ out, int CT, int first, int last) {
  const int idx = blockIdx.x * 256 + threadIdx.x;  // b*C_ + c
  float V, refr, sc;
  int mode;
  if (first) {
    V = 0.f; refr = 0.f; sc = 0.f; mode = 0;
  } else {
    V = Vst[idx]; refr = Rst[idx]; mode = Mst[idx]; sc = SCst[idx];
  }
  const int b = idx >> 9;   // / C_
  const int c = idx & 511;  // % C_
  const float* Ip = I + (size_t)b * CT * C_ + c;

  float bufA[GRP], bufB[GRP];
  const int ng = CT / GRP;

  // prologue: load group 0
#pragma unroll
  for (int j = 0; j < GRP; ++j) bufA[j] = Ip[(size_t)j * C_];

  for (int g = 0; g < ng; g += 2) {
    if (g + 1 < ng) {
      const float* p = Ip + (size_t)(g + 1) * GRP * C_;
#pragma unroll
      for (int j = 0; j < GRP; ++j) bufB[j] = p[(size_t)j * C_];
    }
#pragma unroll
    for (int j = 0; j < GRP; ++j) STEP(bufA[j]);
    if (g + 1 < ng) {
      if (g + 2 < ng) {
        const float* p = Ip + (size_t)(g + 2) * GRP * C_;
#pragma unroll
        for (int j = 0; j < GRP; ++j) bufA[j] = p[(size_t)j * C_];
      }
#pragma unroll
      for (int j = 0; j < GRP; ++j) STEP(bufB[j]);
    }
  }

  if (last) {
    out[idx] = sc;
  } else {
    Vst[idx] = V; Rst[idx] = refr; Mst[idx] = mode; SCst[idx] = sc;
  }
}

// ---------------------------------------------------------------------------
extern "C" void kernel_launch(void* const* d_in, const int* in_sizes, int n_in,
                              void* d_out, int out_size, void* d_ws,
                              size_t ws_size, hipStream_t stream) {
  const float* X = (const float*)d_in[0];   // [B_, T_, F_]
  const float* Wm = (const float*)d_in[1];  // [F_, C_]
  float* out = (float*)d_out;               // [B_, C_]

  const size_t stbytes = (size_t)4 * B_ * C_ * sizeof(float);

  // Pick largest T-chunk whose I-buffer (+state) fits in d_ws.
  int CT = 256, lct = 8;
  while (CT > 16) {
    const size_t need = (size_t)B_ * CT * C_ * sizeof(float) + stbytes;
    if (need <= ws_size) break;
    CT >>= 1;
    --lct;
  }

  float* Ibuf = (float*)d_ws;
  char* sb = (char*)d_ws + (size_t)B_ * CT * C_ * sizeof(float);
  float* Vst = (float*)sb;
  float* Rst = Vst + B_ * C_;
  float* SCst = Rst + B_ * C_;
  int* Mst = (int*)(SCst + B_ * C_);

  const dim3 ggrid(B_ * CT / BM, C_ / BN);
  for (int t0 = 0; t0 < T_; t0 += CT) {
    snn_gemm_kernel<<<ggrid, 256, 0, stream>>>(X, Wm, Ibuf, t0, CT, lct);
    snn_scan_kernel<<<(B_ * C_) / 256, 256, 0, stream>>>(
        Ibuf, Vst, Rst, Mst, SCst, out, CT, t0 == 0, (t0 + CT) == T_);
  }
}

// Round 3
// 585.104 us; speedup vs baseline: 3.0614x; 3.0614x over previous
//
#include <hip/hip_runtime.h>

// Problem constants
#define B_ 128
#define T_ 256
#define F_ 1024
#define C_ 512

// GEMM tiling: 128x128 block tile, BK=32, 256 threads, 8x8 per thread
#define BM 128
#define BN 128
#define BK 32
#define LDA_ (BM + 4)
#define LDB_ (BN + 4)

// ---------------------------------------------------------------------------
// GEMM: I[m, n] = sum_k X[row(m), k] * W[k, n]
//   m = chunk-local row = b*CT + tt ; global X row = b*T_ + t0 + tt
// Thread (ty,tx) computes rows {ty*4+i, 64+ty*4+i} x cols {tx*4+j, 64+tx*4+j}
// -> all LDS fragment reads are at 16B lane stride = conflict-free.
// NOTE: no min-waves launch bound — (256,4) capped VGPR at 64 and spilled
// the 8x8 accumulator to scratch (R2: 7 GB/dispatch scratch traffic, 4x slower).
// ---------------------------------------------------------------------------
__global__ __launch_bounds__(256) void snn_gemm_kernel(
    const float* __restrict__ X, const float* __restrict__ Wm,
    float* __restrict__ I, int t0, int CT, int lct) {
  __shared__ float As[BK][LDA_];  // transposed: As[k][m]
  __shared__ float Bs[BK][LDB_];

  const int tid = threadIdx.x;
  const int m0 = blockIdx.x * BM;
  const int n0 = blockIdx.y * BN;
  const int ctm1 = CT - 1;

  // Staging: A tile 128x32 = 1024 float4, B tile 32x128 = 1024 float4;
  // each thread owns 4 of each.
  const float* pA[4];
  const float* pB[4];
  int rowA[4], c4A[4], krB[4], cB[4];
#pragma unroll
  for (int j = 0; j < 4; ++j) {
    const int ia = tid + 256 * j;
    rowA[j] = ia >> 3;  // 0..127
    c4A[j] = ia & 7;    // k-group of 4 within BK=32
    const int mg = m0 + rowA[j];
    pA[j] = X + (size_t)((mg >> lct) * T_ + t0 + (mg & ctm1)) * F_ + c4A[j] * 4;
    krB[j] = ia >> 5;      // 0..31
    cB[j] = (ia & 31) * 4; // 0..124
    pB[j] = Wm + (size_t)krB[j] * C_ + n0 + cB[j];
  }

  const int ty = tid >> 4;  // 0..15
  const int tx = tid & 15;  // 0..15

  float4 ra[4], rb[4];
#pragma unroll
  for (int j = 0; j < 4; ++j) {
    ra[j] = *(const float4*)pA[j];
    rb[j] = *(const float4*)pB[j];
  }

  float acc[8][8] = {};

  for (int kt = 0; kt < F_ / BK; ++kt) {
    __syncthreads();
#pragma unroll
    for (int j = 0; j < 4; ++j) {
      As[c4A[j] * 4 + 0][rowA[j]] = ra[j].x;
      As[c4A[j] * 4 + 1][rowA[j]] = ra[j].y;
      As[c4A[j] * 4 + 2][rowA[j]] = ra[j].z;
      As[c4A[j] * 4 + 3][rowA[j]] = ra[j].w;
      *(float4*)&Bs[krB[j]][cB[j]] = rb[j];
    }
    __syncthreads();
    if (kt + 1 < F_ / BK) {
      const int k1 = (kt + 1) * BK;
#pragma unroll
      for (int j = 0; j < 4; ++j) {
        ra[j] = *(const float4*)(pA[j] + k1);
        rb[j] = *(const float4*)(pB[j] + (size_t)k1 * C_);
      }
    }
#pragma unroll
    for (int k = 0; k < BK; ++k) {
      const float4 a0 = *(const float4*)&As[k][ty * 4];
      const float4 a1 = *(const float4*)&As[k][64 + ty * 4];
      const float4 b0 = *(const float4*)&Bs[k][tx * 4];
      const float4 b1 = *(const float4*)&Bs[k][64 + tx * 4];
      const float av[8] = {a0.x, a0.y, a0.z, a0.w, a1.x, a1.y, a1.z, a1.w};
      const float bv[8] = {b0.x, b0.y, b0.z, b0.w, b1.x, b1.y, b1.z, b1.w};
#pragma unroll
      for (int i = 0; i < 8; ++i)
#pragma unroll
        for (int j = 0; j < 8; ++j) acc[i][j] += av[i] * bv[j];
    }
  }

  // epilogue
#pragma unroll
  for (int i = 0; i < 8; ++i) {
    const int m = m0 + ((i < 4) ? (ty * 4 + i) : (64 + ty * 4 + (i - 4)));
    float* op = I + (size_t)m * C_ + n0;
    *(float4*)(op + tx * 4) =
        make_float4(acc[i][0], acc[i][1], acc[i][2], acc[i][3]);
    *(float4*)(op + 64 + tx * 4) =
        make_float4(acc[i][4], acc[i][5], acc[i][6], acc[i][7]);
  }
}

// ---------------------------------------------------------------------------
// Scan: one thread per neuron (b,c). Branchless step (exact fp32 op order of
// the reference) + 32-deep double-buffered register prefetch of I.
// Grid-limited to 1024 waves (1/SIMD) -> ILP is the only latency hiding.
// ---------------------------------------------------------------------------
#define GRP 32

#define STEP(Iv)                                                           \
  {                                                                        \
    const bool is0 = (mode == 0), is1 = (mode == 1), is2 = (mode == 2);    \
    V = is0 ? ((V + (Iv)) - 0.01f) : (is2 ? (V + 0.01f) : V);              \
    V = fmaxf(V, 0.0f);                                                    \
    const bool fired = is0 && ((V - 0.4f) > 0.0f);                         \
    sc += fired ? 1.0f : 0.0f;                                             \
    refr = fired ? 2.0f : (is1 ? fmaxf(refr - 1.0f, 0.0f) : refr);         \
    const bool done = is1 && (refr <= 0.0f);                               \
    const bool back = is2 && (V > 0.0f);                                   \
    V = fired ? 0.0f : V;                                                  \
    mode = fired ? 1 : (done ? 2 : (back ? 0 : mode));                     \
  }

__global__ __launch_bounds__(256) void snn_scan_kernel(
    const float* __restrict__ I, float* __restrict__ Vst,
    float* __restrict__ Rst, int* __restrict__ Mst, float* __restrict__ SCst,
    float* __restrict__ out, int CT, int first, int last) {
  const int idx = blockIdx.x * 256 + threadIdx.x;  // b*C_ + c
  float V, refr, sc;
  int mode;
  if (first) {
    V = 0.f; refr = 0.f; sc = 0.f; mode = 0;
  } else {
    V = Vst[idx]; refr = Rst[idx]; mode = Mst[idx]; sc = SCst[idx];
  }
  const int b = idx >> 9;   // / C_
  const int c = idx & 511;  // % C_
  const float* Ip = I + (size_t)b * CT * C_ + c;

  float bufA[GRP], bufB[GRP];
  const int ng = CT / GRP;

  // prologue: load group 0
#pragma unroll
  for (int j = 0; j < GRP; ++j) bufA[j] = Ip[(size_t)j * C_];

  for (int g = 0; g < ng; g += 2) {
    if (g + 1 < ng) {
      const float* p = Ip + (size_t)(g + 1) * GRP * C_;
#pragma unroll
      for (int j = 0; j < GRP; ++j) bufB[j] = p[(size_t)j * C_];
    }
#pragma unroll
    for (int j = 0; j < GRP; ++j) STEP(bufA[j]);
    if (g + 1 < ng) {
      if (g + 2 < ng) {
        const float* p = Ip + (size_t)(g + 2) * GRP * C_;
#pragma unroll
        for (int j = 0; j < GRP; ++j) bufA[j] = p[(size_t)j * C_];
      }
#pragma unroll
      for (int j = 0; j < GRP; ++j) STEP(bufB[j]);
    }
  }

  if (last) {
    out[idx] = sc;
  } else {
    Vst[idx] = V; Rst[idx] = refr; Mst[idx] = mode; SCst[idx] = sc;
  }
}

// ---------------------------------------------------------------------------
extern "C" void kernel_launch(void* const* d_in, const int* in_sizes, int n_in,
                              void* d_out, int out_size, void* d_ws,
                              size_t ws_size, hipStream_t stream) {
  const float* X = (const float*)d_in[0];   // [B_, T_, F_]
  const float* Wm = (const float*)d_in[1];  // [F_, C_]
  float* out = (float*)d_out;               // [B_, C_]

  const size_t stbytes = (size_t)4 * B_ * C_ * sizeof(float);

  // Pick largest T-chunk whose I-buffer (+state) fits in d_ws.
  int CT = 256, lct = 8;
  while (CT > 16) {
    const size_t need = (size_t)B_ * CT * C_ * sizeof(float) + stbytes;
    if (need <= ws_size) break;
    CT >>= 1;
    --lct;
  }

  float* Ibuf = (float*)d_ws;
  char* sb = (char*)d_ws + (size_t)B_ * CT * C_ * sizeof(float);
  float* Vst = (float*)sb;
  float* Rst = Vst + B_ * C_;
  float* SCst = Rst + B_ * C_;
  int* Mst = (int*)(SCst + B_ * C_);

  const dim3 ggrid(B_ * CT / BM, C_ / BN);
  for (int t0 = 0; t0 < T_; t0 += CT) {
    snn_gemm_kernel<<<ggrid, 256, 0, stream>>>(X, Wm, Ibuf, t0, CT, lct);
    snn_scan_kernel<<<(B_ * C_) / 256, 256, 0, stream>>>(
        Ibuf, Vst, Rst, Mst, SCst, out, CT, t0 == 0, (t0 + CT) == T_);
  }
}

// Round 4
// 364.926 us; speedup vs baseline: 4.9085x; 1.6033x over previous
//
#include <hip/hip_runtime.h>

// Problem constants
#define B_ 128
#define T_ 256
#define F_ 1024
#define C_ 512
#define K_ F_

typedef _Float16 f16;
typedef f16 f16x8 __attribute__((ext_vector_type(8)));
typedef f16 f16x4 __attribute__((ext_vector_type(4)));
typedef float f32x4 __attribute__((ext_vector_type(4)));

// ---------------------------------------------------------------------------
// W split + transpose: W[K][N] f32 -> WhiT[N][K] f16, WloT[N][K] f16 (x4096)
// ---------------------------------------------------------------------------
__global__ __launch_bounds__(256) void wsplit_kernel(
    const float* __restrict__ W, f16* __restrict__ WhiT,
    f16* __restrict__ WloT) {
  __shared__ float tile[32][33];
  const int k0 = blockIdx.x * 32;
  const int n0 = blockIdx.y * 32;
  const int tid = threadIdx.x;
#pragma unroll
  for (int j = 0; j < 4; ++j) {
    const int e = tid + 256 * j;
    const int r = e >> 5, c = e & 31;
    tile[r][c] = W[(size_t)(k0 + r) * C_ + n0 + c];
  }
  __syncthreads();
#pragma unroll
  for (int j = 0; j < 4; ++j) {
    const int e = tid + 256 * j;
    const int nn = e >> 5, kk = e & 31;
    const float w = tile[kk][nn];
    const f16 wh = (f16)w;
    const f16 wl = (f16)((w - (float)wh) * 4096.0f);
    WhiT[(size_t)(n0 + nn) * K_ + k0 + kk] = wh;
    WloT[(size_t)(n0 + nn) * K_ + k0 + kk] = wl;
  }
}

// ---------------------------------------------------------------------------
// X split: X[b][t0+tt][f] f32 -> Ahi[m][f], Alo[m][f] f16 (m = b*CT+tt)
// ---------------------------------------------------------------------------
__global__ __launch_bounds__(256) void xsplit_kernel(
    const float* __restrict__ X, f16* __restrict__ Ahi, f16* __restrict__ Alo,
    int t0, int lct, int total4) {
  const int ctm1 = (1 << lct) - 1;
  for (int i4 = blockIdx.x * 256 + threadIdx.x; i4 < total4;
       i4 += gridDim.x * 256) {
    const int m = i4 >> 8;  // / (K_/4)
    const int f4 = (i4 & 255) * 4;
    const int xrow = (m >> lct) * T_ + t0 + (m & ctm1);
    const float4 v = *(const float4*)(X + (size_t)xrow * F_ + f4);
    const f16 h0 = (f16)v.x, h1 = (f16)v.y, h2 = (f16)v.z, h3 = (f16)v.w;
    const f16 l0 = (f16)((v.x - (float)h0) * 4096.0f);
    const f16 l1 = (f16)((v.y - (float)h1) * 4096.0f);
    const f16 l2 = (f16)((v.z - (float)h2) * 4096.0f);
    const f16 l3 = (f16)((v.w - (float)h3) * 4096.0f);
    f16x4 hv = {h0, h1, h2, h3};
    f16x4 lv = {l0, l1, l2, l3};
    *(f16x4*)(Ahi + (size_t)m * K_ + f4) = hv;
    *(f16x4*)(Alo + (size_t)m * K_ + f4) = lv;
  }
}

// ---------------------------------------------------------------------------
// MFMA GEMM: I = Ahi@Whi + 2^-12 * (Alo@Whi + Ahi@Wlo)
// 128x128 tile, 4 waves (2x2 of 64x64), 16x16x32 f16 MFMA, BK=32.
// LDS rows padded to 40 f16 (80B = 5 x 16B slots -> bank-conflict-free).
// Reg-staged (padding breaks global_load_lds linear-dest requirement).
// ---------------------------------------------------------------------------
#define LDT 40  // padded row length in f16

__global__ __launch_bounds__(256) void snn_gemm_mfma(
    const f16* __restrict__ Ahi, const f16* __restrict__ Alo,
    const f16* __restrict__ WhiT, const f16* __restrict__ WloT,
    float* __restrict__ I) {
  __shared__ f16 sAh[128 * LDT];
  __shared__ f16 sAl[128 * LDT];
  __shared__ f16 sBh[128 * LDT];
  __shared__ f16 sBl[128 * LDT];

  const int tid = threadIdx.x;
  const int m0 = blockIdx.x * 128;
  const int n0 = blockIdx.y * 128;
  const int lane = tid & 63;
  const int w = tid >> 6;
  const int wm = (w >> 1) * 64, wn = (w & 1) * 64;

  // Staging: each thread owns rows r0 and r0+64, slot s0 (8 f16 = 16B).
  const int r0 = tid >> 2, s0 = (tid & 3) * 8;
  const f16* gAh0 = Ahi + (size_t)(m0 + r0) * K_ + s0;
  const f16* gAl0 = Alo + (size_t)(m0 + r0) * K_ + s0;
  const f16* gBh0 = WhiT + (size_t)(n0 + r0) * K_ + s0;
  const f16* gBl0 = WloT + (size_t)(n0 + r0) * K_ + s0;
  const size_t gstep = (size_t)64 * K_;
  const int wr0 = r0 * LDT + s0;
  const int wr1 = (r0 + 64) * LDT + s0;

  uint4 vAh0 = *(const uint4*)(gAh0);
  uint4 vAh1 = *(const uint4*)(gAh0 + gstep);
  uint4 vAl0 = *(const uint4*)(gAl0);
  uint4 vAl1 = *(const uint4*)(gAl0 + gstep);
  uint4 vBh0 = *(const uint4*)(gBh0);
  uint4 vBh1 = *(const uint4*)(gBh0 + gstep);
  uint4 vBl0 = *(const uint4*)(gBl0);
  uint4 vBl1 = *(const uint4*)(gBl0 + gstep);

  f32x4 acc0[4][4] = {};
  f32x4 acc1[4][4] = {};

  for (int kt = 0; kt < K_ / 32; ++kt) {
    __syncthreads();
    *(uint4*)&sAh[wr0] = vAh0;
    *(uint4*)&sAh[wr1] = vAh1;
    *(uint4*)&sAl[wr0] = vAl0;
    *(uint4*)&sAl[wr1] = vAl1;
    *(uint4*)&sBh[wr0] = vBh0;
    *(uint4*)&sBh[wr1] = vBh1;
    *(uint4*)&sBl[wr0] = vBl0;
    *(uint4*)&sBl[wr1] = vBl1;
    __syncthreads();
    if (kt + 1 < K_ / 32) {
      const int ko = (kt + 1) * 32;
      vAh0 = *(const uint4*)(gAh0 + ko);
      vAh1 = *(const uint4*)(gAh0 + gstep + ko);
      vAl0 = *(const uint4*)(gAl0 + ko);
      vAl1 = *(const uint4*)(gAl0 + gstep + ko);
      vBh0 = *(const uint4*)(gBh0 + ko);
      vBh1 = *(const uint4*)(gBh0 + gstep + ko);
      vBl0 = *(const uint4*)(gBl0 + ko);
      vBl1 = *(const uint4*)(gBl0 + gstep + ko);
    }
    const int lrow = lane & 15;
    const int sl = (lane >> 4) * 8;
    f16x8 Bh[4], Bl[4];
#pragma unroll
    for (int fn = 0; fn < 4; ++fn) {
      const int nrow = (wn + fn * 16 + lrow) * LDT + sl;
      Bh[fn] = *(const f16x8*)&sBh[nrow];
      Bl[fn] = *(const f16x8*)&sBl[nrow];
    }
#pragma unroll
    for (int fm = 0; fm < 4; ++fm) {
      const int mrow = (wm + fm * 16 + lrow) * LDT + sl;
      const f16x8 Ah = *(const f16x8*)&sAh[mrow];
      const f16x8 Al = *(const f16x8*)&sAl[mrow];
#pragma unroll
      for (int fn = 0; fn < 4; ++fn) {
        acc0[fm][fn] = __builtin_amdgcn_mfma_f32_16x16x32_f16(
            Ah, Bh[fn], acc0[fm][fn], 0, 0, 0);
        acc1[fm][fn] = __builtin_amdgcn_mfma_f32_16x16x32_f16(
            Al, Bh[fn], acc1[fm][fn], 0, 0, 0);
        acc1[fm][fn] = __builtin_amdgcn_mfma_f32_16x16x32_f16(
            Ah, Bl[fn], acc1[fm][fn], 0, 0, 0);
      }
    }
  }

  // Epilogue: D row = 4*(lane>>4)+i, col = lane&15 ; combine the two scales.
  const int er = (lane >> 4) * 4;
  const int ec = lane & 15;
#pragma unroll
  for (int fm = 0; fm < 4; ++fm)
#pragma unroll
    for (int fn = 0; fn < 4; ++fn) {
      float* op =
          I + (size_t)(m0 + wm + fm * 16 + er) * C_ + n0 + wn + fn * 16 + ec;
#pragma unroll
      for (int i = 0; i < 4; ++i)
        op[(size_t)i * C_] = acc0[fm][fn][i] + acc1[fm][fn][i] * (1.0f / 4096.0f);
    }
}

// ---------------------------------------------------------------------------
// Scan: one thread per neuron (b,c). Branchless step (exact fp32 op order of
// the reference) + 32-deep double-buffered register prefetch of I.
// ---------------------------------------------------------------------------
#define GRP 32

#define STEP(Iv)                                                           \
  {                                                                        \
    const bool is0 = (mode == 0), is1 = (mode == 1), is2 = (mode == 2);    \
    V = is0 ? ((V + (Iv)) - 0.01f) : (is2 ? (V + 0.01f) : V);              \
    V = fmaxf(V, 0.0f);                                                    \
    const bool fired = is0 && ((V - 0.4f) > 0.0f);                         \
    sc += fired ? 1.0f : 0.0f;                                             \
    refr = fired ? 2.0f : (is1 ? fmaxf(refr - 1.0f, 0.0f) : refr);         \
    const bool done = is1 && (refr <= 0.0f);                               \
    const bool back = is2 && (V > 0.0f);                                   \
    V = fired ? 0.0f : V;                                                  \
    mode = fired ? 1 : (done ? 2 : (back ? 0 : mode));                     \
  }

__global__ __launch_bounds__(256) void snn_scan_kernel(
    const float* __restrict__ I, float* __restrict__ Vst,
    float* __restrict__ Rst, int* __restrict__ Mst, float* __restrict__ SCst,
    float* __restrict__ out, int CT, int first, int last) {
  const int idx = blockIdx.x * 256 + threadIdx.x;  // b*C_ + c
  float V, refr, sc;
  int mode;
  if (first) {
    V = 0.f; refr = 0.f; sc = 0.f; mode = 0;
  } else {
    V = Vst[idx]; refr = Rst[idx]; mode = Mst[idx]; sc = SCst[idx];
  }
  const int b = idx >> 9;   // / C_
  const int c = idx & 511;  // % C_
  const float* Ip = I + (size_t)b * CT * C_ + c;

  float bufA[GRP], bufB[GRP];
  const int ng = CT / GRP;

#pragma unroll
  for (int j = 0; j < GRP; ++j) bufA[j] = Ip[(size_t)j * C_];

  for (int g = 0; g < ng; g += 2) {
    if (g + 1 < ng) {
      const float* p = Ip + (size_t)(g + 1) * GRP * C_;
#pragma unroll
      for (int j = 0; j < GRP; ++j) bufB[j] = p[(size_t)j * C_];
    }
#pragma unroll
    for (int j = 0; j < GRP; ++j) STEP(bufA[j]);
    if (g + 1 < ng) {
      if (g + 2 < ng) {
        const float* p = Ip + (size_t)(g + 2) * GRP * C_;
#pragma unroll
        for (int j = 0; j < GRP; ++j) bufA[j] = p[(size_t)j * C_];
      }
#pragma unroll
      for (int j = 0; j < GRP; ++j) STEP(bufB[j]);
    }
  }

  if (last) {
    out[idx] = sc;
  } else {
    Vst[idx] = V; Rst[idx] = refr; Mst[idx] = mode; SCst[idx] = sc;
  }
}

// ---------------------------------------------------------------------------
extern "C" void kernel_launch(void* const* d_in, const int* in_sizes, int n_in,
                              void* d_out, int out_size, void* d_ws,
                              size_t ws_size, hipStream_t stream) {
  const float* X = (const float*)d_in[0];   // [B_, T_, F_]
  const float* Wm = (const float*)d_in[1];  // [F_, C_]
  float* out = (float*)d_out;               // [B_, C_]

  // Pick largest T-chunk fitting ws: I + Ahi/Alo + WhiT/WloT + state.
  int CT = 256, lct = 8;
  while (CT > 16) {
    const size_t need = (size_t)B_ * CT * C_ * 4        // I
                        + (size_t)2 * B_ * CT * K_ * 2  // Ahi, Alo
                        + (size_t)2 * C_ * K_ * 2       // WhiT, WloT
                        + (size_t)4 * B_ * C_ * 4;      // state
    if (need <= ws_size) break;
    CT >>= 1;
    --lct;
  }

  char* p = (char*)d_ws;
  float* Ibuf = (float*)p; p += (size_t)B_ * CT * C_ * 4;
  f16* Ahi = (f16*)p; p += (size_t)B_ * CT * K_ * 2;
  f16* Alo = (f16*)p; p += (size_t)B_ * CT * K_ * 2;
  f16* WhiT = (f16*)p; p += (size_t)C_ * K_ * 2;
  f16* WloT = (f16*)p; p += (size_t)C_ * K_ * 2;
  float* Vst = (float*)p;
  float* Rst = Vst + B_ * C_;
  float* SCst = Rst + B_ * C_;
  int* Mst = (int*)(SCst + B_ * C_);

  wsplit_kernel<<<dim3(K_ / 32, C_ / 32), 256, 0, stream>>>(Wm, WhiT, WloT);

  const int total4 = B_ * CT * (K_ / 4);
  const dim3 ggrid(B_ * CT / 128, C_ / 128);
  for (int t0 = 0; t0 < T_; t0 += CT) {
    xsplit_kernel<<<2048, 256, 0, stream>>>(X, Ahi, Alo, t0, lct, total4);
    snn_gemm_mfma<<<ggrid, 256, 0, stream>>>(Ahi, Alo, WhiT, WloT, Ibuf);
    snn_scan_kernel<<<(B_ * C_) / 256, 256, 0, stream>>>(
        Ibuf, Vst, Rst, Mst, SCst, out, CT, t0 == 0, (t0 + CT) == T_);
  }
}

// Round 5
// 339.916 us; speedup vs baseline: 5.2696x; 1.0736x over previous
//
#include <hip/hip_runtime.h>

// Problem constants
#define B_ 128
#define T_ 256
#define F_ 1024
#define C_ 512
#define K_ F_

typedef _Float16 f16;
typedef f16 f16x8 __attribute__((ext_vector_type(8)));
typedef float f32x4 __attribute__((ext_vector_type(4)));

// ---------------------------------------------------------------------------
// W split + transpose: W[K][N] f32 -> WhiT[N][K] f16, WloT[N][K] f16 (x4096)
// ---------------------------------------------------------------------------
__global__ __launch_bounds__(256) void wsplit_kernel(
    const float* __restrict__ W, f16* __restrict__ WhiT,
    f16* __restrict__ WloT) {
  __shared__ float tile[32][33];
  const int k0 = blockIdx.x * 32;
  const int n0 = blockIdx.y * 32;
  const int tid = threadIdx.x;
#pragma unroll
  for (int j = 0; j < 4; ++j) {
    const int e = tid + 256 * j;
    const int r = e >> 5, c = e & 31;
    tile[r][c] = W[(size_t)(k0 + r) * C_ + n0 + c];
  }
  __syncthreads();
#pragma unroll
  for (int j = 0; j < 4; ++j) {
    const int e = tid + 256 * j;
    const int nn = e >> 5, kk = e & 31;
    const float w = tile[kk][nn];
    const f16 wh = (f16)w;
    const f16 wl = (f16)((w - (float)wh) * 4096.0f);
    WhiT[(size_t)(n0 + nn) * K_ + k0 + kk] = wh;
    WloT[(size_t)(n0 + nn) * K_ + k0 + kk] = wl;
  }
}

// ---------------------------------------------------------------------------
// Fused MFMA GEMM: I = X@W via split  X = Xhi + 2^-12 Xlo (f16),
// I = Xhi@Whi + 2^-12 (Xlo@Whi + Xhi@Wlo).
// A-side hi/lo split is done IN-REGISTER from f32 X during staging
// (eliminates the xsplit kernel and its 256MB round-trip).
// 128x128 tile, 4 waves (2x2 of 64x64), 16x16x32 f16 MFMA, BK=32.
// LDS rows padded to 40 f16 (80B = 5 x 16B slots -> bank-conflict-free).
// ---------------------------------------------------------------------------
#define LDT 40  // padded row length in f16

__global__ __launch_bounds__(256) void snn_gemm_mfma(
    const float* __restrict__ X, const f16* __restrict__ WhiT,
    const f16* __restrict__ WloT, float* __restrict__ I) {
  __shared__ f16 sAh[128 * LDT];
  __shared__ f16 sAl[128 * LDT];
  __shared__ f16 sBh[128 * LDT];
  __shared__ f16 sBl[128 * LDT];

  const int tid = threadIdx.x;
  const int m0 = blockIdx.x * 128;
  const int n0 = blockIdx.y * 128;
  const int lane = tid & 63;
  const int w = tid >> 6;
  const int wm = (w >> 1) * 64, wn = (w & 1) * 64;

  // Staging: each thread owns A rows r0, r0+64 (8 f32 each) and B rows
  // r0, r0+64 (8 f16 each from both WhiT and WloT).
  const int r0 = tid >> 2, s0 = (tid & 3) * 8;
  const float* gA0 = X + (size_t)(m0 + r0) * K_ + s0;       // CT==T: identity row map
  const float* gA1 = X + (size_t)(m0 + r0 + 64) * K_ + s0;
  const f16* gBh0 = WhiT + (size_t)(n0 + r0) * K_ + s0;
  const f16* gBl0 = WloT + (size_t)(n0 + r0) * K_ + s0;
  const size_t gstepB = (size_t)64 * K_;
  const int wr0 = r0 * LDT + s0;
  const int wr1 = (r0 + 64) * LDT + s0;

  float4 xa0, xa1, xb0, xb1;
  uint4 vBh0, vBh1, vBl0, vBl1;
  f16x8 Ah0, Al0, Ah1, Al1;

  // split helper: 8 f32 -> 8 f16 hi + 8 f16 lo (x4096) — matches wsplit math
#define SPLIT8(p0, p1, H, L)                                   \
  {                                                            \
    const float v_[8] = {(p0).x, (p0).y, (p0).z, (p0).w,       \
                         (p1).x, (p1).y, (p1).z, (p1).w};      \
    _Pragma("unroll") for (int j_ = 0; j_ < 8; ++j_) {         \
      const f16 h_ = (f16)v_[j_];                              \
      (H)[j_] = h_;                                            \
      (L)[j_] = (f16)((v_[j_] - (float)h_) * 4096.0f);         \
    }                                                          \
  }

  // prologue: load + convert tile 0
  xa0 = *(const float4*)(gA0);
  xa1 = *(const float4*)(gA0 + 4);
  xb0 = *(const float4*)(gA1);
  xb1 = *(const float4*)(gA1 + 4);
  vBh0 = *(const uint4*)(gBh0);
  vBh1 = *(const uint4*)(gBh0 + gstepB);
  vBl0 = *(const uint4*)(gBl0);
  vBl1 = *(const uint4*)(gBl0 + gstepB);
  SPLIT8(xa0, xa1, Ah0, Al0);
  SPLIT8(xb0, xb1, Ah1, Al1);

  f32x4 acc0[4][4] = {};
  f32x4 acc1[4][4] = {};

  for (int kt = 0; kt < K_ / 32; ++kt) {
    __syncthreads();
    *(f16x8*)&sAh[wr0] = Ah0;
    *(f16x8*)&sAh[wr1] = Ah1;
    *(f16x8*)&sAl[wr0] = Al0;
    *(f16x8*)&sAl[wr1] = Al1;
    *(uint4*)&sBh[wr0] = vBh0;
    *(uint4*)&sBh[wr1] = vBh1;
    *(uint4*)&sBl[wr0] = vBl0;
    *(uint4*)&sBl[wr1] = vBl1;
    __syncthreads();
    const bool more = (kt + 1 < K_ / 32);
    if (more) {
      const int ko = (kt + 1) * 32;
      xa0 = *(const float4*)(gA0 + ko);
      xa1 = *(const float4*)(gA0 + ko + 4);
      xb0 = *(const float4*)(gA1 + ko);
      xb1 = *(const float4*)(gA1 + ko + 4);
      vBh0 = *(const uint4*)(gBh0 + ko);
      vBh1 = *(const uint4*)(gBh0 + gstepB + ko);
      vBl0 = *(const uint4*)(gBl0 + ko);
      vBl1 = *(const uint4*)(gBl0 + gstepB + ko);
    }
    const int lrow = lane & 15;
    const int sl = (lane >> 4) * 8;
    f16x8 Bh[4], Bl[4];
#pragma unroll
    for (int fn = 0; fn < 4; ++fn) {
      const int nrow = (wn + fn * 16 + lrow) * LDT + sl;
      Bh[fn] = *(const f16x8*)&sBh[nrow];
      Bl[fn] = *(const f16x8*)&sBl[nrow];
    }
#pragma unroll
    for (int fm = 0; fm < 4; ++fm) {
      const int mrow = (wm + fm * 16 + lrow) * LDT + sl;
      const f16x8 Ah = *(const f16x8*)&sAh[mrow];
      const f16x8 Al = *(const f16x8*)&sAl[mrow];
#pragma unroll
      for (int fn = 0; fn < 4; ++fn) {
        acc0[fm][fn] = __builtin_amdgcn_mfma_f32_16x16x32_f16(
            Ah, Bh[fn], acc0[fm][fn], 0, 0, 0);
        acc1[fm][fn] = __builtin_amdgcn_mfma_f32_16x16x32_f16(
            Al, Bh[fn], acc1[fm][fn], 0, 0, 0);
        acc1[fm][fn] = __builtin_amdgcn_mfma_f32_16x16x32_f16(
            Ah, Bl[fn], acc1[fm][fn], 0, 0, 0);
      }
    }
    // convert next tile's A (overlaps with MFMA tail; regs free after LDS write)
    if (more) {
      SPLIT8(xa0, xa1, Ah0, Al0);
      SPLIT8(xb0, xb1, Ah1, Al1);
    }
  }

  // Epilogue: D row = 4*(lane>>4)+i, col = lane&15 ; combine the two scales.
  const int er = (lane >> 4) * 4;
  const int ec = lane & 15;
#pragma unroll
  for (int fm = 0; fm < 4; ++fm)
#pragma unroll
    for (int fn = 0; fn < 4; ++fn) {
      float* op =
          I + (size_t)(m0 + wm + fm * 16 + er) * C_ + n0 + wn + fn * 16 + ec;
#pragma unroll
      for (int i = 0; i < 4; ++i)
        op[(size_t)i * C_] = acc0[fm][fn][i] + acc1[fm][fn][i] * (1.0f / 4096.0f);
    }
}

// ---------------------------------------------------------------------------
// Scan: block-cooperative LDS staging. Each block owns 256 neurons
// (b = bid>>1, c in [c0, c0+256)). Per 64-step tile: stream 64 x 1KB rows
// of I coalesced into LDS (16 float4/thread), barrier, then each thread
// walks its LDS column (bank tid%32 -> 2-way, free). Exact STEP arithmetic.
// ---------------------------------------------------------------------------
#define TT 64

#define STEP(Iv)                                                           \
  {                                                                        \
    const bool is0 = (mode == 0), is1 = (mode == 1), is2 = (mode == 2);    \
    V = is0 ? ((V + (Iv)) - 0.01f) : (is2 ? (V + 0.01f) : V);              \
    V = fmaxf(V, 0.0f);                                                    \
    const bool fired = is0 && ((V - 0.4f) > 0.0f);                         \
    sc += fired ? 1.0f : 0.0f;                                             \
    refr = fired ? 2.0f : (is1 ? fmaxf(refr - 1.0f, 0.0f) : refr);         \
    const bool done = is1 && (refr <= 0.0f);                               \
    const bool back = is2 && (V > 0.0f);                                   \
    V = fired ? 0.0f : V;                                                  \
    mode = fired ? 1 : (done ? 2 : (back ? 0 : mode));                     \
  }

__global__ __launch_bounds__(256) void snn_scan_kernel(
    const float* __restrict__ I, float* __restrict__ out) {
  __shared__ float tile[TT * 256];
  const int tid = threadIdx.x;
  const int bid = blockIdx.x;
  const int b = bid >> 1;
  const int c0 = (bid & 1) << 8;
  const float* Ib = I + (size_t)b * T_ * C_ + c0;

  float V = 0.f, refr = 0.f, sc = 0.f;
  int mode = 0;

  for (int tg = 0; tg < T_ / TT; ++tg) {
    // stage: 16 float4 per thread, coalesced 1KB rows
    float4 st[16];
#pragma unroll
    for (int i = 0; i < 16; ++i) {
      const int flat4 = i * 256 + tid;
      const int row = flat4 >> 6, col4 = flat4 & 63;
      st[i] = *(const float4*)(Ib + (size_t)(tg * TT + row) * C_ + col4 * 4);
    }
    __syncthreads();  // previous tile's compute done before overwrite
#pragma unroll
    for (int i = 0; i < 16; ++i) {
      const int flat4 = i * 256 + tid;
      *(float4*)&tile[flat4 * 4] = st[i];
    }
    __syncthreads();  // tile visible
#pragma unroll
    for (int tt = 0; tt < TT; ++tt) {
      const float Iv = tile[tt * 256 + tid];
      STEP(Iv);
    }
  }
  out[bid * 256 + tid] = sc;
}

// ---------------------------------------------------------------------------
extern "C" void kernel_launch(void* const* d_in, const int* in_sizes, int n_in,
                              void* d_out, int out_size, void* d_ws,
                              size_t ws_size, hipStream_t stream) {
  const float* X = (const float*)d_in[0];   // [B_, T_, F_] = [B_*T_][F_]
  const float* Wm = (const float*)d_in[1];  // [F_, C_]
  float* out = (float*)d_out;               // [B_, C_]

  // ws layout: I (64MB) + WhiT (1MB) + WloT (1MB)  — ws >= 195MB per R4.
  char* p = (char*)d_ws;
  float* Ibuf = (float*)p; p += (size_t)B_ * T_ * C_ * sizeof(float);
  f16* WhiT = (f16*)p; p += (size_t)C_ * K_ * sizeof(f16);
  f16* WloT = (f16*)p;

  wsplit_kernel<<<dim3(K_ / 32, C_ / 32), 256, 0, stream>>>(Wm, WhiT, WloT);
  snn_gemm_mfma<<<dim3(B_ * T_ / 128, C_ / 128), 256, 0, stream>>>(
      X, WhiT, WloT, Ibuf);
  snn_scan_kernel<<<B_ * C_ / 256, 256, 0, stream>>>(Ibuf, out);
}

// Round 6
// 328.061 us; speedup vs baseline: 5.4601x; 1.0361x over previous
//
#include <hip/hip_runtime.h>

// Problem constants
#define B_ 128
#define T_ 256
#define F_ 1024
#define C_ 512
#define K_ F_

typedef _Float16 f16;
typedef f16 f16x8 __attribute__((ext_vector_type(8)));
typedef float f32x4 __attribute__((ext_vector_type(4)));

// ---------------------------------------------------------------------------
// W split + transpose: W[K][N] f32 -> WhiT[N][K] f16, WloT[N][K] f16 (x4096)
// ---------------------------------------------------------------------------
__global__ __launch_bounds__(256) void wsplit_kernel(
    const float* __restrict__ W, f16* __restrict__ WhiT,
    f16* __restrict__ WloT) {
  __shared__ float tile[32][33];
  const int k0 = blockIdx.x * 32;
  const int n0 = blockIdx.y * 32;
  const int tid = threadIdx.x;
#pragma unroll
  for (int j = 0; j < 4; ++j) {
    const int e = tid + 256 * j;
    const int r = e >> 5, c = e & 31;
    tile[r][c] = W[(size_t)(k0 + r) * C_ + n0 + c];
  }
  __syncthreads();
#pragma unroll
  for (int j = 0; j < 4; ++j) {
    const int e = tid + 256 * j;
    const int nn = e >> 5, kk = e & 31;
    const float w = tile[kk][nn];
    const f16 wh = (f16)w;
    const f16 wl = (f16)((w - (float)wh) * 4096.0f);
    WhiT[(size_t)(n0 + nn) * K_ + k0 + kk] = wh;
    WloT[(size_t)(n0 + nn) * K_ + k0 + kk] = wl;
  }
}

// ---------------------------------------------------------------------------
// Fused MFMA GEMM (unchanged from R5): I = Xhi@Whi + 2^-12 (Xlo@Whi + Xhi@Wlo)
// 128x128 tile, 4 waves (2x2 of 64x64), 16x16x32 f16 MFMA, BK=32.
// ---------------------------------------------------------------------------
#define LDT 40  // padded row length in f16

__global__ __launch_bounds__(256) void snn_gemm_mfma(
    const float* __restrict__ X, const f16* __restrict__ WhiT,
    const f16* __restrict__ WloT, float* __restrict__ I) {
  __shared__ f16 sAh[128 * LDT];
  __shared__ f16 sAl[128 * LDT];
  __shared__ f16 sBh[128 * LDT];
  __shared__ f16 sBl[128 * LDT];

  const int tid = threadIdx.x;
  const int m0 = blockIdx.x * 128;
  const int n0 = blockIdx.y * 128;
  const int lane = tid & 63;
  const int w = tid >> 6;
  const int wm = (w >> 1) * 64, wn = (w & 1) * 64;

  const int r0 = tid >> 2, s0 = (tid & 3) * 8;
  const float* gA0 = X + (size_t)(m0 + r0) * K_ + s0;
  const float* gA1 = X + (size_t)(m0 + r0 + 64) * K_ + s0;
  const f16* gBh0 = WhiT + (size_t)(n0 + r0) * K_ + s0;
  const f16* gBl0 = WloT + (size_t)(n0 + r0) * K_ + s0;
  const size_t gstepB = (size_t)64 * K_;
  const int wr0 = r0 * LDT + s0;
  const int wr1 = (r0 + 64) * LDT + s0;

  float4 xa0, xa1, xb0, xb1;
  uint4 vBh0, vBh1, vBl0, vBl1;
  f16x8 Ah0, Al0, Ah1, Al1;

#define SPLIT8(p0, p1, H, L)                                   \
  {                                                            \
    const float v_[8] = {(p0).x, (p0).y, (p0).z, (p0).w,       \
                         (p1).x, (p1).y, (p1).z, (p1).w};      \
    _Pragma("unroll") for (int j_ = 0; j_ < 8; ++j_) {         \
      const f16 h_ = (f16)v_[j_];                              \
      (H)[j_] = h_;                                            \
      (L)[j_] = (f16)((v_[j_] - (float)h_) * 4096.0f);         \
    }                                                          \
  }

  xa0 = *(const float4*)(gA0);
  xa1 = *(const float4*)(gA0 + 4);
  xb0 = *(const float4*)(gA1);
  xb1 = *(const float4*)(gA1 + 4);
  vBh0 = *(const uint4*)(gBh0);
  vBh1 = *(const uint4*)(gBh0 + gstepB);
  vBl0 = *(const uint4*)(gBl0);
  vBl1 = *(const uint4*)(gBl0 + gstepB);
  SPLIT8(xa0, xa1, Ah0, Al0);
  SPLIT8(xb0, xb1, Ah1, Al1);

  f32x4 acc0[4][4] = {};
  f32x4 acc1[4][4] = {};

  for (int kt = 0; kt < K_ / 32; ++kt) {
    __syncthreads();
    *(f16x8*)&sAh[wr0] = Ah0;
    *(f16x8*)&sAh[wr1] = Ah1;
    *(f16x8*)&sAl[wr0] = Al0;
    *(f16x8*)&sAl[wr1] = Al1;
    *(uint4*)&sBh[wr0] = vBh0;
    *(uint4*)&sBh[wr1] = vBh1;
    *(uint4*)&sBl[wr0] = vBl0;
    *(uint4*)&sBl[wr1] = vBl1;
    __syncthreads();
    const bool more = (kt + 1 < K_ / 32);
    if (more) {
      const int ko = (kt + 1) * 32;
      xa0 = *(const float4*)(gA0 + ko);
      xa1 = *(const float4*)(gA0 + ko + 4);
      xb0 = *(const float4*)(gA1 + ko);
      xb1 = *(const float4*)(gA1 + ko + 4);
      vBh0 = *(const uint4*)(gBh0 + ko);
      vBh1 = *(const uint4*)(gBh0 + gstepB + ko);
      vBl0 = *(const uint4*)(gBl0 + ko);
      vBl1 = *(const uint4*)(gBl0 + gstepB + ko);
    }
    const int lrow = lane & 15;
    const int sl = (lane >> 4) * 8;
    f16x8 Bh[4], Bl[4];
#pragma unroll
    for (int fn = 0; fn < 4; ++fn) {
      const int nrow = (wn + fn * 16 + lrow) * LDT + sl;
      Bh[fn] = *(const f16x8*)&sBh[nrow];
      Bl[fn] = *(const f16x8*)&sBl[nrow];
    }
#pragma unroll
    for (int fm = 0; fm < 4; ++fm) {
      const int mrow = (wm + fm * 16 + lrow) * LDT + sl;
      const f16x8 Ah = *(const f16x8*)&sAh[mrow];
      const f16x8 Al = *(const f16x8*)&sAl[mrow];
#pragma unroll
      for (int fn = 0; fn < 4; ++fn) {
        acc0[fm][fn] = __builtin_amdgcn_mfma_f32_16x16x32_f16(
            Ah, Bh[fn], acc0[fm][fn], 0, 0, 0);
        acc1[fm][fn] = __builtin_amdgcn_mfma_f32_16x16x32_f16(
            Al, Bh[fn], acc1[fm][fn], 0, 0, 0);
        acc1[fm][fn] = __builtin_amdgcn_mfma_f32_16x16x32_f16(
            Ah, Bl[fn], acc1[fm][fn], 0, 0, 0);
      }
    }
    if (more) {
      SPLIT8(xa0, xa1, Ah0, Al0);
      SPLIT8(xb0, xb1, Ah1, Al1);
    }
  }

  const int er = (lane >> 4) * 4;
  const int ec = lane & 15;
#pragma unroll
  for (int fm = 0; fm < 4; ++fm)
#pragma unroll
    for (int fn = 0; fn < 4; ++fn) {
      float* op =
          I + (size_t)(m0 + wm + fm * 16 + er) * C_ + n0 + wn + fn * 16 + ec;
#pragma unroll
      for (int i = 0; i < 4; ++i)
        op[(size_t)i * C_] = acc0[fm][fn][i] + acc1[fm][fn][i] * (1.0f / 4096.0f);
    }
}

// ---------------------------------------------------------------------------
// Scan v3: 512 blocks x 128 threads; block = (b = bid>>2, cols (bid&3)*128..).
// TT=32 tile in 16KB LDS + REGISTER double-buffer: next tile's 8 float4
// global loads issue right after the LDS-write barrier and retire under the
// current tile's 32 STEPs (issue-early/write-late). Exact STEP arithmetic.
// ---------------------------------------------------------------------------
#define TTS 32

#define STEP(Iv)                                                           \
  {                                                                        \
    const bool is0 = (mode == 0), is1 = (mode == 1), is2 = (mode == 2);    \
    V = is0 ? ((V + (Iv)) - 0.01f) : (is2 ? (V + 0.01f) : V);              \
    V = fmaxf(V, 0.0f);                                                    \
    const bool fired = is0 && ((V - 0.4f) > 0.0f);                         \
    sc += fired ? 1.0f : 0.0f;                                             \
    refr = fired ? 2.0f : (is1 ? fmaxf(refr - 1.0f, 0.0f) : refr);         \
    const bool done = is1 && (refr <= 0.0f);                               \
    const bool back = is2 && (V > 0.0f);                                   \
    V = fired ? 0.0f : V;                                                  \
    mode = fired ? 1 : (done ? 2 : (back ? 0 : mode));                     \
  }

__global__ __launch_bounds__(128) void snn_scan_kernel(
    const float* __restrict__ I, float* __restrict__ out) {
  __shared__ float tile[TTS * 128];  // 16KB
  const int tid = threadIdx.x;
  const int bid = blockIdx.x;
  const int b = bid >> 2;
  const int c0 = (bid & 3) << 7;
  const float* Ib = I + (size_t)b * T_ * C_ + c0;

  float V = 0.f, refr = 0.f, sc = 0.f;
  int mode = 0;

  float4 st[8];
  // prologue: load tile 0 into regs
#pragma unroll
  for (int i = 0; i < 8; ++i) {
    const int f4 = i * 128 + tid;
    const int row = f4 >> 5, c4 = f4 & 31;
    st[i] = *(const float4*)(Ib + (size_t)row * C_ + c4 * 4);
  }

  for (int tg = 0; tg < T_ / TTS; ++tg) {
    __syncthreads();  // previous tile's compute done before overwrite
#pragma unroll
    for (int i = 0; i < 8; ++i) {
      const int f4 = i * 128 + tid;
      *(float4*)&tile[f4 * 4] = st[i];
    }
    __syncthreads();  // tile visible
    if (tg + 1 < T_ / TTS) {
      // issue next tile's loads NOW; they retire under the compute below
      const float* p = Ib + (size_t)(tg + 1) * TTS * C_;
#pragma unroll
      for (int i = 0; i < 8; ++i) {
        const int f4 = i * 128 + tid;
        const int row = f4 >> 5, c4 = f4 & 31;
        st[i] = *(const float4*)(p + (size_t)row * C_ + c4 * 4);
      }
    }
#pragma unroll
    for (int tt = 0; tt < TTS; ++tt) {
      const float Iv = tile[tt * 128 + tid];
      STEP(Iv);
    }
  }
  out[(size_t)b * C_ + c0 + tid] = sc;
}

// ---------------------------------------------------------------------------
extern "C" void kernel_launch(void* const* d_in, const int* in_sizes, int n_in,
                              void* d_out, int out_size, void* d_ws,
                              size_t ws_size, hipStream_t stream) {
  const float* X = (const float*)d_in[0];   // [B_*T_][F_]
  const float* Wm = (const float*)d_in[1];  // [F_, C_]
  float* out = (float*)d_out;               // [B_, C_]

  char* p = (char*)d_ws;
  float* Ibuf = (float*)p; p += (size_t)B_ * T_ * C_ * sizeof(float);
  f16* WhiT = (f16*)p; p += (size_t)C_ * K_ * sizeof(f16);
  f16* WloT = (f16*)p;

  wsplit_kernel<<<dim3(K_ / 32, C_ / 32), 256, 0, stream>>>(Wm, WhiT, WloT);
  snn_gemm_mfma<<<dim3(B_ * T_ / 128, C_ / 128), 256, 0, stream>>>(
      X, WhiT, WloT, Ibuf);
  snn_scan_kernel<<<B_ * C_ / 128, 128, 0, stream>>>(Ibuf, out);
}